// Round 5
// baseline (169.046 us; speedup 1.0000x reference)
//
#include <hip/hip_runtime.h>
#include <math.h>

#define NT 128          // tables_k / peps_main block size (2 waves)
#define NTG 256         // gram kernel block size

struct PW { const float* w[16]; int perp[16]; };

// d_ws float offsets: gram[0..48), TL table @64 (16x1296, [e*16+p]),
// TR @20800, BL @41536, R @62272 (8x1296, [e*8+p]). Total 72640 floats.
#define TLT 64
#define TRT 20800
#define BLT 41536
#define RTT 62272

// ---------------------------------------------------------------------------
// Gram precompute (unchanged, verified): per node n, <w0,w0>,<w0,w1>,<w1,w1>.
// ---------------------------------------------------------------------------
__global__ __launch_bounds__(NTG) void gram16(PW pw, float* __restrict__ g) {
    const int n = blockIdx.x;
    const float* __restrict__ W = pw.w[n];
    const int m = pw.perp[n];
    float s00 = 0.f, s01 = 0.f, s11 = 0.f;
    for (int e = threadIdx.x; e < m; e += NTG) {
        float a = W[e], b = W[m + e];
        s00 += a * a; s01 += a * b; s11 += b * b;
    }
    for (int off = 32; off > 0; off >>= 1) {
        s00 += __shfl_down(s00, off, 64);
        s01 += __shfl_down(s01, off, 64);
        s11 += __shfl_down(s11, off, 64);
    }
    __shared__ float red[4][3];
    const int lane = threadIdx.x & 63, wv = threadIdx.x >> 6;
    if (lane == 0) { red[wv][0] = s00; red[wv][1] = s01; red[wv][2] = s11; }
    __syncthreads();
    if (threadIdx.x == 0) {
        float t0 = 0.f, t1 = 0.f, t2 = 0.f;
        for (int i = 0; i < 4; i++) { t0 += red[i][0]; t1 += red[i][1]; t2 += red[i][2]; }
        g[n * 3 + 0] = t0; g[n * 3 + 1] = t1; g[n * 3 + 2] = t2;
    }
}

// ---------------------------------------------------------------------------
// Generic contraction (round-1 verified template, TX=1, pointer-based).
// ---------------------------------------------------------------------------
template<int X1, int X2, int Y1, int Y2, int U, int L,
         int AX1, int AX2, int AU, int AL,
         int BU, int BLs, int BY1, int BY2,
         int OX1, int OX2, int OY1, int OY2>
__device__ __forceinline__ void contract(const float* __restrict__ A,
                                         const float* __restrict__ Bm,
                                         float* __restrict__ O, int tid) {
    constexpr int ROWS = X1 * X2 * Y1;
    for (int r = tid; r < ROWS; r += NT) {
        const int x1 = r / (X2 * Y1);
        const int rm = r - x1 * (X2 * Y1);
        const int x2 = rm / Y1;
        const int y1 = rm - x2 * Y1;
        const float* __restrict__ Ab = A + x1 * AX1 + x2 * AX2;
        const float* __restrict__ Bb = Bm + y1 * BY1;
        float acc[Y2];
#pragma unroll
        for (int t = 0; t < Y2; t++) acc[t] = 0.f;
#pragma unroll
        for (int u = 0; u < U; u++) {
#pragma unroll
            for (int l = 0; l < L; l++) {
                const float a = Ab[u * AU + l * AL];
                const float* __restrict__ Bp = Bb + u * BU + l * BLs;
#pragma unroll
                for (int t = 0; t < Y2; t++) acc[t] += a * Bp[t * BY2];
            }
        }
        float* __restrict__ Ob = O + x1 * OX1 + x2 * OX2 + y1 * OY1;
#pragma unroll
        for (int t = 0; t < Y2; t++) Ob[t * OY2] = acc[t];
    }
}

// copy selected physical slice of a node into LDS
template<int M, int DST>
__device__ __forceinline__ void csel(float* __restrict__ L, const float* __restrict__ W, int tid) {
    for (int e = tid; e < M; e += NT) L[DST + e] = W[e];
}

// ---------------------------------------------------------------------------
// Pattern-table precompute. 56 blocks: 0-15 TL, 16-31 TR, 32-47 BL, 48-55 R.
// Pattern bit b selects w0/w1 slice of node list[b]; lists must match the γ
// computation in peps_main: TL{0,1,4,5} TR{2,3,7,6} BL{12,8,13,9} R{11,15,14}.
// Table layouts (k-major for the main kernel GEMMs):
//   TL[e=k1*36+m], TR[e=k1*36+n]  k1=(h01,h11), m=(v10,v11), n=(v12,v13)
//   BL[e=m*36+j]   j=(h21,h31);   R[e=k3*36+n'] k3=(v13,h31), n'=(v22,h22)
// ---------------------------------------------------------------------------
__global__ __launch_bounds__(NT) void tables_k(PW pw, float* __restrict__ ws) {
    __shared__ float L[4356];
    constexpr int bA = 0, bB = 1296, bC = 2592, sA = 3888, sB = 4104, sC = 4320;
    const int tid = threadIdx.x, bid = blockIdx.x;
    if (bid < 16) {                 // TL: nodes 00,01,10,11
        const int p = bid;
        csel<36, sC>(L, pw.w[0] + ((p >> 0) & 1) * 36, tid);
        csel<216, sA>(L, pw.w[1] + ((p >> 1) & 1) * 216, tid);
        __syncthreads();
        contract<1,6,6,6,6,1,  0,6,1,0,  36,0,6,1,  0,36,6,1>(L+sC, L+sA, L+sB, tid);
        csel<216, bA>(L, pw.w[4] + ((p >> 2) & 1) * 216, tid);
        __syncthreads();
        contract<1,36,6,6,6,1,  0,1,36,0,  36,0,6,1,  0,36,6,1>(L+sB, L+bA, L+bB, tid);
        csel<1296, bC>(L, pw.w[5] + ((p >> 3) & 1) * 1296, tid);
        __syncthreads();
        contract<6,6,6,6,6,6,  36,6,216,1,  216,36,6,1,  216*16,6*16,1*16,36*16>(L+bB, L+bC, ws + TLT + p, tid);
    } else if (bid < 32) {          // TR: nodes 02,03,13,12
        const int p = bid - 16;
        csel<216, sA>(L, pw.w[2] + ((p >> 0) & 1) * 216, tid);
        csel<36, sC>(L, pw.w[3] + ((p >> 1) & 1) * 36, tid);
        __syncthreads();
        contract<1,36,1,6,6,1,  0,6,1,0,  6,0,0,1,  0,6,0,1>(L+sA, L+sC, L+sB, tid);
        csel<216, bA>(L, pw.w[7] + ((p >> 2) & 1) * 216, tid);
        __syncthreads();
        contract<1,36,6,6,6,1,  0,6,1,0,  36,0,6,1,  0,36,6,1>(L+sB, L+bA, L+bB, tid);
        csel<1296, bC>(L, pw.w[6] + ((p >> 3) & 1) * 1296, tid);
        __syncthreads();
        contract<6,6,6,6,6,6,  36,6,216,1,  36,6,216,1,  36*16,6*16,216*16,1*16>(L+bC, L+bB, ws + TRT + p, tid);
    } else if (bid < 48) {          // BL: nodes 30,20,31,21
        const int p = bid - 32;
        csel<36, sC>(L, pw.w[12] + ((p >> 0) & 1) * 36, tid);
        csel<216, sA>(L, pw.w[8] + ((p >> 1) & 1) * 216, tid);
        __syncthreads();
        contract<1,6,6,6,6,1,  0,1,6,0,  6,0,36,1,  0,36,6,1>(L+sC, L+sA, L+sB, tid);
        csel<216, bA>(L, pw.w[13] + ((p >> 2) & 1) * 216, tid);
        __syncthreads();
        contract<1,36,6,6,6,1,  0,1,36,0,  6,0,36,1,  0,36,6,1>(L+sB, L+bA, L+bB, tid);
        csel<1296, bC>(L, pw.w[9] + ((p >> 3) & 1) * 1296, tid);
        __syncthreads();
        contract<6,6,6,6,6,6,  216,1,36,6,  36,6,216,1,  216*16,1*16,36*16,6*16>(L+bB, L+bC, ws + BLT + p, tid);
    } else {                        // R: nodes 23,33,32
        const int p = bid - 48;
        csel<216, sA>(L, pw.w[11] + ((p >> 0) & 1) * 216, tid);
        csel<36, sC>(L, pw.w[15] + ((p >> 1) & 1) * 36, tid);
        __syncthreads();
        contract<6,6,1,6,6,1,  36,6,1,0,  6,0,0,1,  36,6,0,1>(L+sA, L+sC, L+sB, tid);
        csel<216, bA>(L, pw.w[14] + ((p >> 2) & 1) * 216, tid);
        __syncthreads();
        contract<6,6,6,6,6,1,  36,6,1,0,  1,0,36,6,  216*8,1*8,6*8,36*8>(L+sB, L+bA, ws + RTT + p, tid);
    }
}

// ---------------------------------------------------------------------------
// Main kernel pieces. Arena: 2 samples x 4 buffers of 1296.
// ---------------------------------------------------------------------------
constexpr int AR = 5184;   // per-sample arena floats (4 x 1296)

// Q[e] = sum_p gamma[p] * tab[e*PC+p] for both samples (table read shared).
template<int PC, int DST, int GOFF>
__device__ __forceinline__ void sweep(float* __restrict__ lds, const float* __restrict__ tab,
                                      const float* __restrict__ gam, int tid) {
    float g0[PC], g1[PC];
#pragma unroll
    for (int c = 0; c < PC; c++) { g0[c] = gam[GOFF + c]; g1[c] = gam[56 + GOFF + c]; }
    for (int e = tid; e < 1296; e += NT) {
        const float4* __restrict__ tp = (const float4*)(tab + e * PC);
        float a0 = 0.f, a1 = 0.f;
#pragma unroll
        for (int c = 0; c < PC / 4; c++) {
            const float4 v = tp[c];
            a0 += v.x * g0[4*c] + v.y * g0[4*c+1] + v.z * g0[4*c+2] + v.w * g0[4*c+3];
            a1 += v.x * g1[4*c] + v.y * g1[4*c+1] + v.z * g1[4*c+2] + v.w * g1[4*c+3];
        }
        lds[DST + e] = a0;
        lds[AR + DST + e] = a1;
    }
}

// C[x,y] = sum_k A[k*36+x] * B[k*36+y]  (both k-major), out via 4 strides with
// x = xh*6+xl, y = yh*6+yl. Thread tile: 2(x) x 12(y); b64 A + 3x b128 B reads.
template<int SXH, int SXL, int SYH, int SYL, int AOFF, int BOFF, int OOFF>
__device__ __forceinline__ void kmm(float* __restrict__ lds, int tid) {
    for (int t = tid; t < 108; t += NT) {      // 2 samples x 54 tiles
        const int sl = t / 54;
        const int r = t - sl * 54;
        const int xg = r / 3, yg = r - xg * 3;
        const int x0 = xg * 2, y0 = yg * 12;
        const float* __restrict__ A = lds + sl * AR + AOFF;
        const float* __restrict__ B = lds + sl * AR + BOFF;
        float acc0[12], acc1[12];
#pragma unroll
        for (int j = 0; j < 12; j++) { acc0[j] = 0.f; acc1[j] = 0.f; }
#pragma unroll
        for (int k = 0; k < 36; k++) {
            const float2 a = *(const float2*)(A + k * 36 + x0);
            const float* __restrict__ Bp = B + k * 36 + y0;
            const float4 v0 = *(const float4*)(Bp);
            const float4 v1 = *(const float4*)(Bp + 4);
            const float4 v2 = *(const float4*)(Bp + 8);
            const float bv[12] = {v0.x,v0.y,v0.z,v0.w, v1.x,v1.y,v1.z,v1.w, v2.x,v2.y,v2.z,v2.w};
#pragma unroll
            for (int j = 0; j < 12; j++) {
                acc0[j] += a.x * bv[j];
                acc1[j] += a.y * bv[j];
            }
        }
        float* __restrict__ O = lds + sl * AR + OOFF;
#pragma unroll
        for (int i = 0; i < 2; i++) {
            const int xx = x0 + i;
            const int xh = xx / 6, xl = xx - xh * 6;
#pragma unroll
            for (int j = 0; j < 12; j++) {
                const int yy = y0 + j;
                const int yh = yy / 6, yl = yy - yh * 6;
                O[xh * SXH + xl * SXL + yh * SYH + yl * SYL] = (i == 0) ? acc0[j] : acc1[j];
            }
        }
    }
}

// ---------------------------------------------------------------------------
// Main: one block = 2 samples. Quadrants from tables, then TOP, M1, E, out.
// ---------------------------------------------------------------------------
__global__ __launch_bounds__(NT) void peps_main(const float* __restrict__ x, PW pw,
                                                const float* __restrict__ ws,
                                                float* __restrict__ out) {
    __shared__ float arena[2 * AR];
    __shared__ float cfa[2][16], cfb[2][16];
    __shared__ float gam[2 * 56];

    const int tid = threadIdx.x;
    const int s0 = blockIdx.x * 2;
    const float* __restrict__ gram = ws;

    // normalized per-node coefficients (t = ca*w0 + cb*w1, unit norm)
    if (tid < 32) {
        const int sl = tid >> 4, n = tid & 15;
        const float a = x[(s0 + sl) * 32 + n * 2 + 0];
        const float b = x[(s0 + sl) * 32 + n * 2 + 1];
        const float g0 = gram[n*3+0], g1 = gram[n*3+1], g2 = gram[n*3+2];
        const float inv = 1.f / sqrtf(a*a*g0 + 2.f*a*b*g1 + b*b*g2);
        cfa[sl][n] = a * inv; cfb[sl][n] = b * inv;
    }
    __syncthreads();

    // gamma products per quadrant pattern (must match tables_k node lists)
    if (tid < 112) {
        const int sl = tid / 56, u = tid - sl * 56;
        int p, nl0, nl1, nl2, nl3, nb;
        if (u < 16)      { p = u;      nl0 = 0;  nl1 = 1;  nl2 = 4;  nl3 = 5; nb = 4; }
        else if (u < 32) { p = u - 16; nl0 = 2;  nl1 = 3;  nl2 = 7;  nl3 = 6; nb = 4; }
        else if (u < 48) { p = u - 32; nl0 = 12; nl1 = 8;  nl2 = 13; nl3 = 9; nb = 4; }
        else             { p = u - 48; nl0 = 11; nl1 = 15; nl2 = 14; nl3 = 0; nb = 3; }
        float gv = ((p >> 0) & 1) ? cfb[sl][nl0] : cfa[sl][nl0];
        gv      *= ((p >> 1) & 1) ? cfb[sl][nl1] : cfa[sl][nl1];
        gv      *= ((p >> 2) & 1) ? cfb[sl][nl2] : cfa[sl][nl2];
        if (nb == 4) gv *= ((p >> 3) & 1) ? cfb[sl][nl3] : cfa[sl][nl3];
        gam[sl * 56 + u] = gv;
    }
    __syncthreads();

    // P1: quadrant tensors from tables  (TL->b0, TR->b1, BL->b3)
    sweep<16, 0,    0>(arena, ws + TLT, gam, tid);
    sweep<16, 1296, 16>(arena, ws + TRT, gam, tid);
    sweep<16, 3888, 32>(arena, ws + BLT, gam, tid);
    __syncthreads();
    // P2: TOP[m][n] = sum_k1 TL[k1][m]*TR[k1][n]   -> b2 (m-major)
    kmm<216, 36, 6, 1,  0, 1296, 2592>(arena, tid);
    __syncthreads();
    // P3: M1[(v13,h31)][(v12,h21)] = sum_m TOP[m][n]*BL[m][j] -> b0 (scattered)
    //     + sweep R' -> b1
    kmm<6, 216, 1, 36,  2592, 3888, 0>(arena, tid);
    sweep<8, 1296, 48>(arena, ws + RTT, gam, tid);
    __syncthreads();
    // P4: E[m'][n'] = sum_k3 M1[k3][m']*R'[k3][n'] -> b2
    kmm<216, 36, 6, 1,  0, 1296, 2592>(arena, tid);
    __syncthreads();

    // epilogue: one wave per sample; out[o] = sum_e E[e]*(ca*w0[e,o]+cb*w1[e,o])
    {
        const int lane = tid & 63, sl = tid >> 6;
        const float al = cfa[sl][10], be = cfb[sl][10];
        const float* __restrict__ w0 = pw.w[10];
        const float* __restrict__ w1 = w0 + 12960;
        const float* __restrict__ E = arena + sl * AR + 2592;
        float p[10];
#pragma unroll
        for (int o = 0; o < 10; o++) p[o] = 0.f;
        for (int e = lane; e < 1296; e += 64) {
            const float Ev = E[e];
            const float* __restrict__ q0 = w0 + e * 10;
            const float* __restrict__ q1 = w1 + e * 10;
#pragma unroll
            for (int o = 0; o < 10; o++) p[o] += Ev * (al * q0[o] + be * q1[o]);
        }
#pragma unroll
        for (int o = 0; o < 10; o++)
            for (int off = 32; off > 0; off >>= 1)
                p[o] += __shfl_down(p[o], off, 64);
        if (lane == 0) {
            float ss = 0.f;
#pragma unroll
            for (int o = 0; o < 10; o++) ss += p[o] * p[o];
            const float inv = 1.f / sqrtf(ss);
#pragma unroll
            for (int o = 0; o < 10; o++) out[(s0 + sl) * 10 + o] = p[o] * inv;
        }
    }
}

extern "C" void kernel_launch(void* const* d_in, const int* in_sizes, int n_in,
                              void* d_out, int out_size, void* d_ws, size_t ws_size,
                              hipStream_t stream) {
    PW pw;
    for (int k = 0; k < 16; k++) {
        pw.w[k] = (const float*)d_in[1 + k];
        pw.perp[k] = in_sizes[1 + k] / 2;
    }
    float* ws = (float*)d_ws;               // 72640 floats used (~291 KB)
    gram16<<<16, NTG, 0, stream>>>(pw, ws);
    tables_k<<<56, NT, 0, stream>>>(pw, ws);

    const float* x = (const float*)d_in[0];
    const int B = out_size / 10;            // 2048 samples
    peps_main<<<B / 2, NT, 0, stream>>>(x, pw, ws, (float*)d_out);
}

// Round 6
// 164.924 us; speedup vs baseline: 1.0250x; 1.0250x over previous
//
#include <hip/hip_runtime.h>
#include <math.h>

#define NT 128   // prep (tables+gram) block size
#define NS 64    // main kernel block size: ONE wave

struct PW { const float* w[16]; int perp[16]; };

// d_ws float offsets: gram[0..48), TL table @64 (16x1296, [e*16+p]),
// TR @20800, BL @41536, R @62272 (8x1296, [e*8+p]). Total 72640 floats.
#define TLT 64
#define TRT 20800
#define BLT 41536
#define RTT 62272

// ---------------------------------------------------------------------------
// Generic contraction (round-1/5 verified template), NT threads.
// ---------------------------------------------------------------------------
template<int X1, int X2, int Y1, int Y2, int U, int L,
         int AX1, int AX2, int AU, int AL,
         int BU, int BLs, int BY1, int BY2,
         int OX1, int OX2, int OY1, int OY2>
__device__ __forceinline__ void contract(const float* __restrict__ A,
                                         const float* __restrict__ Bm,
                                         float* __restrict__ O, int tid) {
    constexpr int ROWS = X1 * X2 * Y1;
    for (int r = tid; r < ROWS; r += NT) {
        const int x1 = r / (X2 * Y1);
        const int rm = r - x1 * (X2 * Y1);
        const int x2 = rm / Y1;
        const int y1 = rm - x2 * Y1;
        const float* __restrict__ Ab = A + x1 * AX1 + x2 * AX2;
        const float* __restrict__ Bb = Bm + y1 * BY1;
        float acc[Y2];
#pragma unroll
        for (int t = 0; t < Y2; t++) acc[t] = 0.f;
#pragma unroll
        for (int u = 0; u < U; u++) {
#pragma unroll
            for (int l = 0; l < L; l++) {
                const float a = Ab[u * AU + l * AL];
                const float* __restrict__ Bp = Bb + u * BU + l * BLs;
#pragma unroll
                for (int t = 0; t < Y2; t++) acc[t] += a * Bp[t * BY2];
            }
        }
        float* __restrict__ Ob = O + x1 * OX1 + x2 * OX2 + y1 * OY1;
#pragma unroll
        for (int t = 0; t < Y2; t++) Ob[t * OY2] = acc[t];
    }
}

template<int M, int DST>
__device__ __forceinline__ void csel(float* __restrict__ L, const float* __restrict__ W, int tid) {
    for (int e = tid; e < M; e += NT) L[DST + e] = W[e];
}

// ---------------------------------------------------------------------------
// prep: blocks 0-55 = pattern tables (round-5 verified), blocks 56-71 = gram.
// ---------------------------------------------------------------------------
__global__ __launch_bounds__(NT) void prep(PW pw, float* __restrict__ ws) {
    __shared__ float L[4356];
    constexpr int bA = 0, bB = 1296, bC = 2592, sA = 3888, sB = 4104, sC = 4320;
    const int tid = threadIdx.x, bid = blockIdx.x;
    if (bid < 16) {                 // TL: nodes 00,01,10,11
        const int p = bid;
        csel<36, sC>(L, pw.w[0] + ((p >> 0) & 1) * 36, tid);
        csel<216, sA>(L, pw.w[1] + ((p >> 1) & 1) * 216, tid);
        __syncthreads();
        contract<1,6,6,6,6,1,  0,6,1,0,  36,0,6,1,  0,36,6,1>(L+sC, L+sA, L+sB, tid);
        csel<216, bA>(L, pw.w[4] + ((p >> 2) & 1) * 216, tid);
        __syncthreads();
        contract<1,36,6,6,6,1,  0,1,36,0,  36,0,6,1,  0,36,6,1>(L+sB, L+bA, L+bB, tid);
        csel<1296, bC>(L, pw.w[5] + ((p >> 3) & 1) * 1296, tid);
        __syncthreads();
        contract<6,6,6,6,6,6,  36,6,216,1,  216,36,6,1,  216*16,6*16,1*16,36*16>(L+bB, L+bC, ws + TLT + p, tid);
    } else if (bid < 32) {          // TR: nodes 02,03,13,12
        const int p = bid - 16;
        csel<216, sA>(L, pw.w[2] + ((p >> 0) & 1) * 216, tid);
        csel<36, sC>(L, pw.w[3] + ((p >> 1) & 1) * 36, tid);
        __syncthreads();
        contract<1,36,1,6,6,1,  0,6,1,0,  6,0,0,1,  0,6,0,1>(L+sA, L+sC, L+sB, tid);
        csel<216, bA>(L, pw.w[7] + ((p >> 2) & 1) * 216, tid);
        __syncthreads();
        contract<1,36,6,6,6,1,  0,6,1,0,  36,0,6,1,  0,36,6,1>(L+sB, L+bA, L+bB, tid);
        csel<1296, bC>(L, pw.w[6] + ((p >> 3) & 1) * 1296, tid);
        __syncthreads();
        contract<6,6,6,6,6,6,  36,6,216,1,  36,6,216,1,  36*16,6*16,216*16,1*16>(L+bC, L+bB, ws + TRT + p, tid);
    } else if (bid < 48) {          // BL: nodes 30,20,31,21
        const int p = bid - 32;
        csel<36, sC>(L, pw.w[12] + ((p >> 0) & 1) * 36, tid);
        csel<216, sA>(L, pw.w[8] + ((p >> 1) & 1) * 216, tid);
        __syncthreads();
        contract<1,6,6,6,6,1,  0,1,6,0,  6,0,36,1,  0,36,6,1>(L+sC, L+sA, L+sB, tid);
        csel<216, bA>(L, pw.w[13] + ((p >> 2) & 1) * 216, tid);
        __syncthreads();
        contract<1,36,6,6,6,1,  0,1,36,0,  6,0,36,1,  0,36,6,1>(L+sB, L+bA, L+bB, tid);
        csel<1296, bC>(L, pw.w[9] + ((p >> 3) & 1) * 1296, tid);
        __syncthreads();
        contract<6,6,6,6,6,6,  216,1,36,6,  36,6,216,1,  216*16,1*16,36*16,6*16>(L+bB, L+bC, ws + BLT + p, tid);
    } else if (bid < 56) {          // R: nodes 23,33,32
        const int p = bid - 48;
        csel<216, sA>(L, pw.w[11] + ((p >> 0) & 1) * 216, tid);
        csel<36, sC>(L, pw.w[15] + ((p >> 1) & 1) * 36, tid);
        __syncthreads();
        contract<6,6,1,6,6,1,  36,6,1,0,  6,0,0,1,  36,6,0,1>(L+sA, L+sC, L+sB, tid);
        csel<216, bA>(L, pw.w[14] + ((p >> 2) & 1) * 216, tid);
        __syncthreads();
        contract<6,6,6,6,6,1,  36,6,1,0,  1,0,36,6,  216*8,1*8,6*8,36*8>(L+sB, L+bA, ws + RTT + p, tid);
    } else {                        // gram for node n = bid-56
        const int n = bid - 56;
        const float* __restrict__ W = pw.w[n];
        const int m = pw.perp[n];
        float s00 = 0.f, s01 = 0.f, s11 = 0.f;
        for (int e = tid; e < m; e += NT) {
            float a = W[e], b = W[m + e];
            s00 += a * a; s01 += a * b; s11 += b * b;
        }
        for (int off = 32; off > 0; off >>= 1) {
            s00 += __shfl_down(s00, off, 64);
            s01 += __shfl_down(s01, off, 64);
            s11 += __shfl_down(s11, off, 64);
        }
        const int lane = tid & 63, wv = tid >> 6;
        if (lane == 0) { L[wv * 3 + 0] = s00; L[wv * 3 + 1] = s01; L[wv * 3 + 2] = s11; }
        __syncthreads();
        if (tid == 0) {
            ws[n * 3 + 0] = L[0] + L[3];
            ws[n * 3 + 1] = L[1] + L[4];
            ws[n * 3 + 2] = L[2] + L[5];
        }
    }
}

// ---------------------------------------------------------------------------
// Main-kernel helpers (single wave, single sample).
// ---------------------------------------------------------------------------

// dst[e] = sum_p gam[GOFF+p] * tab[e*PC+p]
template<int PC, int GOFF>
__device__ __forceinline__ void sweep1(float* __restrict__ dst, const float* __restrict__ tab,
                                       const float* __restrict__ gam, int tid) {
    float g[PC];
#pragma unroll
    for (int c = 0; c < PC; c++) g[c] = gam[GOFF + c];
    for (int e = tid; e < 1296; e += NS) {
        const float4* __restrict__ tp = (const float4*)(tab + e * PC);
        float a = 0.f;
#pragma unroll
        for (int c = 0; c < PC / 4; c++) {
            const float4 v = tp[c];
            a += v.x * g[4*c] + v.y * g[4*c+1] + v.z * g[4*c+2] + v.w * g[4*c+3];
        }
        dst[e] = a;
    }
}

// C[x,y] = sum_k A[k*36+x]*B[k*36+y] (k-major inputs); one 2x12 tile per lane
// (54 tiles <= 64 lanes). Output scattered via 4 strides (round-5 verified).
template<int SXH, int SXL, int SYH, int SYL>
__device__ __forceinline__ void kmm1(const float* __restrict__ A, const float* __restrict__ B,
                                     float* __restrict__ O, int tid) {
    if (tid < 54) {
        const int xg = tid / 3, yg = tid - xg * 3;
        const int x0 = xg * 2, y0 = yg * 12;
        float acc0[12], acc1[12];
#pragma unroll
        for (int j = 0; j < 12; j++) { acc0[j] = 0.f; acc1[j] = 0.f; }
#pragma unroll
        for (int k = 0; k < 36; k++) {
            const float2 a = *(const float2*)(A + k * 36 + x0);
            const float* __restrict__ Bp = B + k * 36 + y0;
            const float4 v0 = *(const float4*)(Bp);
            const float4 v1 = *(const float4*)(Bp + 4);
            const float4 v2 = *(const float4*)(Bp + 8);
            const float bv[12] = {v0.x,v0.y,v0.z,v0.w, v1.x,v1.y,v1.z,v1.w, v2.x,v2.y,v2.z,v2.w};
#pragma unroll
            for (int j = 0; j < 12; j++) {
                acc0[j] += a.x * bv[j];
                acc1[j] += a.y * bv[j];
            }
        }
#pragma unroll
        for (int i = 0; i < 2; i++) {
            const int xx = x0 + i;
            const int xh = xx / 6, xl = xx - xh * 6;
#pragma unroll
            for (int j = 0; j < 12; j++) {
                const int yy = y0 + j;
                const int yh = yy / 6, yl = yy - yh * 6;
                O[xh * SXH + xl * SXL + yh * SYH + yl * SYL] = (i == 0) ? acc0[j] : acc1[j];
            }
        }
    }
}

// ---------------------------------------------------------------------------
// Main: one block = one sample = ONE wave. 3 renamed LDS buffers (15.9 KB):
//   TL->A, TR->B, TOP=kmm(A,B)->C, BL->A, M1=kmm(C,A)->B, R'->C,
//   E=kmm(B,C)->A, epilogue from A. Every kmm writes a non-input buffer.
// ---------------------------------------------------------------------------
__global__ __launch_bounds__(NS) void peps_main(const float* __restrict__ x, PW pw,
                                                const float* __restrict__ ws,
                                                float* __restrict__ out) {
    __shared__ float A[1296], B[1296], C[1296];
    __shared__ float cfa[16], cfb[16], gam[56];

    const int tid = threadIdx.x;
    const int s = blockIdx.x;
    const float* __restrict__ gram = ws;

    // normalized per-node coefficients (t = ca*w0 + cb*w1, unit norm)
    if (tid < 16) {
        const float a = x[s * 32 + tid * 2 + 0];
        const float b = x[s * 32 + tid * 2 + 1];
        const float g0 = gram[tid*3+0], g1 = gram[tid*3+1], g2 = gram[tid*3+2];
        const float inv = 1.f / sqrtf(a*a*g0 + 2.f*a*b*g1 + b*b*g2);
        cfa[tid] = a * inv; cfb[tid] = b * inv;
    }
    __syncthreads();

    // gamma products (must match prep's node lists; round-5 verified)
    if (tid < 56) {
        const int u = tid;
        int p, nl0, nl1, nl2, nl3, nb;
        if (u < 16)      { p = u;      nl0 = 0;  nl1 = 1;  nl2 = 4;  nl3 = 5; nb = 4; }
        else if (u < 32) { p = u - 16; nl0 = 2;  nl1 = 3;  nl2 = 7;  nl3 = 6; nb = 4; }
        else if (u < 48) { p = u - 32; nl0 = 12; nl1 = 8;  nl2 = 13; nl3 = 9; nb = 4; }
        else             { p = u - 48; nl0 = 11; nl1 = 15; nl2 = 14; nl3 = 0; nb = 3; }
        float gv = ((p >> 0) & 1) ? cfb[nl0] : cfa[nl0];
        gv      *= ((p >> 1) & 1) ? cfb[nl1] : cfa[nl1];
        gv      *= ((p >> 2) & 1) ? cfb[nl2] : cfa[nl2];
        if (nb == 4) gv *= ((p >> 3) & 1) ? cfb[nl3] : cfa[nl3];
        gam[u] = gv;
    }
    __syncthreads();

    sweep1<16, 0>(A, ws + TLT, gam, tid);   // TL -> A
    sweep1<16, 16>(B, ws + TRT, gam, tid);  // TR -> B
    __syncthreads();
    kmm1<216, 36, 6, 1>(A, B, C, tid);      // TOP -> C
    __syncthreads();
    sweep1<16, 32>(A, ws + BLT, gam, tid);  // BL -> A (TL dead)
    __syncthreads();
    kmm1<6, 216, 1, 36>(C, A, B, tid);      // M1 -> B (TR dead)
    __syncthreads();
    sweep1<8, 48>(C, ws + RTT, gam, tid);   // R' -> C (TOP dead)
    __syncthreads();
    kmm1<216, 36, 6, 1>(B, C, A, tid);      // E -> A (BL dead)
    __syncthreads();

    // epilogue: out[o] = sum_e E[e]*(ca*w0[e,o]+cb*w1[e,o]); L2-normalize
    {
        const float al = cfa[10], be = cfb[10];
        const float* __restrict__ w0 = pw.w[10];
        const float* __restrict__ w1 = w0 + 12960;
        float p[10];
#pragma unroll
        for (int o = 0; o < 10; o++) p[o] = 0.f;
        for (int e = tid; e < 1296; e += NS) {
            const float Ev = A[e];
            const float* __restrict__ q0 = w0 + e * 10;
            const float* __restrict__ q1 = w1 + e * 10;
#pragma unroll
            for (int o = 0; o < 10; o++) p[o] += Ev * (al * q0[o] + be * q1[o]);
        }
#pragma unroll
        for (int o = 0; o < 10; o++)
            for (int off = 32; off > 0; off >>= 1)
                p[o] += __shfl_down(p[o], off, 64);
        if (tid == 0) {
            float ss = 0.f;
#pragma unroll
            for (int o = 0; o < 10; o++) ss += p[o] * p[o];
            const float inv = 1.f / sqrtf(ss);
#pragma unroll
            for (int o = 0; o < 10; o++) out[s * 10 + o] = p[o] * inv;
        }
    }
}

extern "C" void kernel_launch(void* const* d_in, const int* in_sizes, int n_in,
                              void* d_out, int out_size, void* d_ws, size_t ws_size,
                              hipStream_t stream) {
    PW pw;
    for (int k = 0; k < 16; k++) {
        pw.w[k] = (const float*)d_in[1 + k];
        pw.perp[k] = in_sizes[1 + k] / 2;
    }
    float* ws = (float*)d_ws;               // 72640 floats used (~291 KB)
    prep<<<72, NT, 0, stream>>>(pw, ws);

    const float* x = (const float*)d_in[0];
    const int B = out_size / 10;            // 2048 samples
    peps_main<<<B, NS, 0, stream>>>(x, pw, ws, (float*)d_out);
}

// Round 7
// 158.686 us; speedup vs baseline: 1.0653x; 1.0393x over previous
//
#include <hip/hip_runtime.h>
#include <math.h>

#define NT 128   // prep (tables+gram) block size
#define NS 64    // main kernel block size: ONE wave, TWO samples

struct PW { const float* w[16]; int perp[16]; };

// d_ws float offsets: gram[0..48), TL table @64 (16x1296, [e*16+p]),
// TR @20800, BL @41536, R @62272 (8x1296, [e*8+p]). Total 72640 floats.
#define TLT 64
#define TRT 20800
#define BLT 41536
#define RTT 62272

// ---------------------------------------------------------------------------
// Generic contraction (round-1/5 verified template), NT threads.
// ---------------------------------------------------------------------------
template<int X1, int X2, int Y1, int Y2, int U, int L,
         int AX1, int AX2, int AU, int AL,
         int BU, int BLs, int BY1, int BY2,
         int OX1, int OX2, int OY1, int OY2>
__device__ __forceinline__ void contract(const float* __restrict__ A,
                                         const float* __restrict__ Bm,
                                         float* __restrict__ O, int tid) {
    constexpr int ROWS = X1 * X2 * Y1;
    for (int r = tid; r < ROWS; r += NT) {
        const int x1 = r / (X2 * Y1);
        const int rm = r - x1 * (X2 * Y1);
        const int x2 = rm / Y1;
        const int y1 = rm - x2 * Y1;
        const float* __restrict__ Ab = A + x1 * AX1 + x2 * AX2;
        const float* __restrict__ Bb = Bm + y1 * BY1;
        float acc[Y2];
#pragma unroll
        for (int t = 0; t < Y2; t++) acc[t] = 0.f;
#pragma unroll
        for (int u = 0; u < U; u++) {
#pragma unroll
            for (int l = 0; l < L; l++) {
                const float a = Ab[u * AU + l * AL];
                const float* __restrict__ Bp = Bb + u * BU + l * BLs;
#pragma unroll
                for (int t = 0; t < Y2; t++) acc[t] += a * Bp[t * BY2];
            }
        }
        float* __restrict__ Ob = O + x1 * OX1 + x2 * OX2 + y1 * OY1;
#pragma unroll
        for (int t = 0; t < Y2; t++) Ob[t * OY2] = acc[t];
    }
}

template<int M, int DST>
__device__ __forceinline__ void csel(float* __restrict__ L, const float* __restrict__ W, int tid) {
    for (int e = tid; e < M; e += NT) L[DST + e] = W[e];
}

// ---------------------------------------------------------------------------
// prep: blocks 0-55 = pattern tables (round-5/6 verified), 56-71 = gram.
// ---------------------------------------------------------------------------
__global__ __launch_bounds__(NT) void prep(PW pw, float* __restrict__ ws) {
    __shared__ float L[4356];
    constexpr int bA = 0, bB = 1296, bC = 2592, sA = 3888, sB = 4104, sC = 4320;
    const int tid = threadIdx.x, bid = blockIdx.x;
    if (bid < 16) {                 // TL: nodes 00,01,10,11
        const int p = bid;
        csel<36, sC>(L, pw.w[0] + ((p >> 0) & 1) * 36, tid);
        csel<216, sA>(L, pw.w[1] + ((p >> 1) & 1) * 216, tid);
        __syncthreads();
        contract<1,6,6,6,6,1,  0,6,1,0,  36,0,6,1,  0,36,6,1>(L+sC, L+sA, L+sB, tid);
        csel<216, bA>(L, pw.w[4] + ((p >> 2) & 1) * 216, tid);
        __syncthreads();
        contract<1,36,6,6,6,1,  0,1,36,0,  36,0,6,1,  0,36,6,1>(L+sB, L+bA, L+bB, tid);
        csel<1296, bC>(L, pw.w[5] + ((p >> 3) & 1) * 1296, tid);
        __syncthreads();
        contract<6,6,6,6,6,6,  36,6,216,1,  216,36,6,1,  216*16,6*16,1*16,36*16>(L+bB, L+bC, ws + TLT + p, tid);
    } else if (bid < 32) {          // TR: nodes 02,03,13,12
        const int p = bid - 16;
        csel<216, sA>(L, pw.w[2] + ((p >> 0) & 1) * 216, tid);
        csel<36, sC>(L, pw.w[3] + ((p >> 1) & 1) * 36, tid);
        __syncthreads();
        contract<1,36,1,6,6,1,  0,6,1,0,  6,0,0,1,  0,6,0,1>(L+sA, L+sC, L+sB, tid);
        csel<216, bA>(L, pw.w[7] + ((p >> 2) & 1) * 216, tid);
        __syncthreads();
        contract<1,36,6,6,6,1,  0,6,1,0,  36,0,6,1,  0,36,6,1>(L+sB, L+bA, L+bB, tid);
        csel<1296, bC>(L, pw.w[6] + ((p >> 3) & 1) * 1296, tid);
        __syncthreads();
        contract<6,6,6,6,6,6,  36,6,216,1,  36,6,216,1,  36*16,6*16,216*16,1*16>(L+bC, L+bB, ws + TRT + p, tid);
    } else if (bid < 48) {          // BL: nodes 30,20,31,21
        const int p = bid - 32;
        csel<36, sC>(L, pw.w[12] + ((p >> 0) & 1) * 36, tid);
        csel<216, sA>(L, pw.w[8] + ((p >> 1) & 1) * 216, tid);
        __syncthreads();
        contract<1,6,6,6,6,1,  0,1,6,0,  6,0,36,1,  0,36,6,1>(L+sC, L+sA, L+sB, tid);
        csel<216, bA>(L, pw.w[13] + ((p >> 2) & 1) * 216, tid);
        __syncthreads();
        contract<1,36,6,6,6,1,  0,1,36,0,  6,0,36,1,  0,36,6,1>(L+sB, L+bA, L+bB, tid);
        csel<1296, bC>(L, pw.w[9] + ((p >> 3) & 1) * 1296, tid);
        __syncthreads();
        contract<6,6,6,6,6,6,  216,1,36,6,  36,6,216,1,  216*16,1*16,36*16,6*16>(L+bB, L+bC, ws + BLT + p, tid);
    } else if (bid < 56) {          // R: nodes 23,33,32
        const int p = bid - 48;
        csel<216, sA>(L, pw.w[11] + ((p >> 0) & 1) * 216, tid);
        csel<36, sC>(L, pw.w[15] + ((p >> 1) & 1) * 36, tid);
        __syncthreads();
        contract<6,6,1,6,6,1,  36,6,1,0,  6,0,0,1,  36,6,0,1>(L+sA, L+sC, L+sB, tid);
        csel<216, bA>(L, pw.w[14] + ((p >> 2) & 1) * 216, tid);
        __syncthreads();
        contract<6,6,6,6,6,1,  36,6,1,0,  1,0,36,6,  216*8,1*8,6*8,36*8>(L+sB, L+bA, ws + RTT + p, tid);
    } else {                        // gram for node n = bid-56
        const int n = bid - 56;
        const float* __restrict__ W = pw.w[n];
        const int m = pw.perp[n];
        float s00 = 0.f, s01 = 0.f, s11 = 0.f;
        for (int e = tid; e < m; e += NT) {
            float a = W[e], b = W[m + e];
            s00 += a * a; s01 += a * b; s11 += b * b;
        }
        for (int off = 32; off > 0; off >>= 1) {
            s00 += __shfl_down(s00, off, 64);
            s01 += __shfl_down(s01, off, 64);
            s11 += __shfl_down(s11, off, 64);
        }
        const int lane = tid & 63, wv = tid >> 6;
        if (lane == 0) { L[wv * 3 + 0] = s00; L[wv * 3 + 1] = s01; L[wv * 3 + 2] = s11; }
        __syncthreads();
        if (tid == 0) {
            ws[n * 3 + 0] = L[0] + L[3];
            ws[n * 3 + 1] = L[1] + L[4];
            ws[n * 3 + 2] = L[2] + L[5];
        }
    }
}

// ---------------------------------------------------------------------------
// Main-kernel helpers: ONE wave, TWO samples (shared table loads, 2x ILP).
// ---------------------------------------------------------------------------

// dst{0,1}[e] = sum_p gam{0,1}[GOFF+p] * tab[e*PC+p]; table float4 read once.
template<int PC, int GOFF>
__device__ __forceinline__ void sweep2(float* __restrict__ dst0, float* __restrict__ dst1,
                                       const float* __restrict__ tab,
                                       const float* __restrict__ gam, int tid) {
    float g0[PC], g1[PC];
#pragma unroll
    for (int c = 0; c < PC; c++) { g0[c] = gam[GOFF + c]; g1[c] = gam[56 + GOFF + c]; }
    for (int e = tid; e < 1296; e += NS) {
        const float4* __restrict__ tp = (const float4*)(tab + e * PC);
        float a0 = 0.f, a1 = 0.f;
#pragma unroll
        for (int c = 0; c < PC / 4; c++) {
            const float4 v = tp[c];
            a0 += v.x * g0[4*c] + v.y * g0[4*c+1] + v.z * g0[4*c+2] + v.w * g0[4*c+3];
            a1 += v.x * g1[4*c] + v.y * g1[4*c+1] + v.z * g1[4*c+2] + v.w * g1[4*c+3];
        }
        dst0[e] = a0;
        dst1[e] = a1;
    }
}

// C[x,y] = sum_k A[k*36+x]*B[k*36+y] for BOTH samples in one k-loop (2x ILP).
// One 2x12 tile per lane per sample (54 tiles <= 64 lanes). Output scattered
// via the round-5/6 verified 4-stride pattern.
template<int SXH, int SXL, int SYH, int SYL>
__device__ __forceinline__ void kmm2(const float* __restrict__ A0, const float* __restrict__ B0,
                                     float* __restrict__ O0,
                                     const float* __restrict__ A1, const float* __restrict__ B1,
                                     float* __restrict__ O1, int tid) {
    if (tid < 54) {
        const int xg = tid / 3, yg = tid - xg * 3;
        const int x0 = xg * 2, y0 = yg * 12;
        float p00[12], p01[12], p10[12], p11[12];
#pragma unroll
        for (int j = 0; j < 12; j++) { p00[j] = 0.f; p01[j] = 0.f; p10[j] = 0.f; p11[j] = 0.f; }
#pragma unroll
        for (int k = 0; k < 36; k++) {
            const float2 a0 = *(const float2*)(A0 + k * 36 + x0);
            const float2 a1 = *(const float2*)(A1 + k * 36 + x0);
            const float* __restrict__ Bp0 = B0 + k * 36 + y0;
            const float* __restrict__ Bp1 = B1 + k * 36 + y0;
            const float4 u0 = *(const float4*)(Bp0);
            const float4 u1 = *(const float4*)(Bp0 + 4);
            const float4 u2 = *(const float4*)(Bp0 + 8);
            const float4 w0 = *(const float4*)(Bp1);
            const float4 w1 = *(const float4*)(Bp1 + 4);
            const float4 w2 = *(const float4*)(Bp1 + 8);
            const float bv0[12] = {u0.x,u0.y,u0.z,u0.w, u1.x,u1.y,u1.z,u1.w, u2.x,u2.y,u2.z,u2.w};
            const float bv1[12] = {w0.x,w0.y,w0.z,w0.w, w1.x,w1.y,w1.z,w1.w, w2.x,w2.y,w2.z,w2.w};
#pragma unroll
            for (int j = 0; j < 12; j++) {
                p00[j] += a0.x * bv0[j];
                p01[j] += a0.y * bv0[j];
                p10[j] += a1.x * bv1[j];
                p11[j] += a1.y * bv1[j];
            }
        }
#pragma unroll
        for (int i = 0; i < 2; i++) {
            const int xx = x0 + i;
            const int xh = xx / 6, xl = xx - xh * 6;
#pragma unroll
            for (int j = 0; j < 12; j++) {
                const int yy = y0 + j;
                const int yh = yy / 6, yl = yy - yh * 6;
                const int off = xh * SXH + xl * SXL + yh * SYH + yl * SYL;
                O0[off] = (i == 0) ? p00[j] : p01[j];
                O1[off] = (i == 0) ? p10[j] : p11[j];
            }
        }
    }
}

// ---------------------------------------------------------------------------
// Main: one block = one wave = TWO samples. Per-sample 3 renamed buffers:
//   TL->A, TR->B, TOP=kmm(A,B)->C, BL->A, M1=kmm(C,A)->B, R'->C,
//   E=kmm(B,C)->A. Table & w22 loads shared across the two samples.
// ---------------------------------------------------------------------------
__global__ __launch_bounds__(NS) void peps_main(const float* __restrict__ x, PW pw,
                                                const float* __restrict__ ws,
                                                float* __restrict__ out) {
    __shared__ float lds[7776];            // A0,B0,C0,A1,B1,C1 x 1296
    __shared__ float cfa[2][16], cfb[2][16], gam[112];
    float* const A0 = lds;          float* const B0 = lds + 1296; float* const C0 = lds + 2592;
    float* const A1 = lds + 3888;   float* const B1 = lds + 5184; float* const C1 = lds + 6480;

    const int tid = threadIdx.x;
    const int s0 = blockIdx.x * 2;
    const float* __restrict__ gram = ws;

    // normalized per-node coefficients for both samples
    if (tid < 32) {
        const int sl = tid >> 4, n = tid & 15;
        const float a = x[(s0 + sl) * 32 + n * 2 + 0];
        const float b = x[(s0 + sl) * 32 + n * 2 + 1];
        const float g0 = gram[n*3+0], g1 = gram[n*3+1], g2 = gram[n*3+2];
        const float inv = 1.f / sqrtf(a*a*g0 + 2.f*a*b*g1 + b*b*g2);
        cfa[sl][n] = a * inv; cfb[sl][n] = b * inv;
    }
    __syncthreads();

    // gamma products (node lists match prep; round-5/6 verified)
    for (int t = tid; t < 112; t += NS) {
        const int sl = t / 56, u = t - sl * 56;
        int p, nl0, nl1, nl2, nl3, nb;
        if (u < 16)      { p = u;      nl0 = 0;  nl1 = 1;  nl2 = 4;  nl3 = 5; nb = 4; }
        else if (u < 32) { p = u - 16; nl0 = 2;  nl1 = 3;  nl2 = 7;  nl3 = 6; nb = 4; }
        else if (u < 48) { p = u - 32; nl0 = 12; nl1 = 8;  nl2 = 13; nl3 = 9; nb = 4; }
        else             { p = u - 48; nl0 = 11; nl1 = 15; nl2 = 14; nl3 = 0; nb = 3; }
        float gv = ((p >> 0) & 1) ? cfb[sl][nl0] : cfa[sl][nl0];
        gv      *= ((p >> 1) & 1) ? cfb[sl][nl1] : cfa[sl][nl1];
        gv      *= ((p >> 2) & 1) ? cfb[sl][nl2] : cfa[sl][nl2];
        if (nb == 4) gv *= ((p >> 3) & 1) ? cfb[sl][nl3] : cfa[sl][nl3];
        gam[t] = gv;
    }
    __syncthreads();

    sweep2<16, 0>(A0, A1, ws + TLT, gam, tid);    // TL -> A
    sweep2<16, 16>(B0, B1, ws + TRT, gam, tid);   // TR -> B
    __syncthreads();
    kmm2<216, 36, 6, 1>(A0, B0, C0, A1, B1, C1, tid);   // TOP -> C
    __syncthreads();
    sweep2<16, 32>(A0, A1, ws + BLT, gam, tid);   // BL -> A (TL dead)
    __syncthreads();
    kmm2<6, 216, 1, 36>(C0, A0, B0, C1, A1, B1, tid);   // M1 -> B (TR dead)
    __syncthreads();
    sweep2<8, 48>(C0, C1, ws + RTT, gam, tid);    // R' -> C (TOP dead)
    __syncthreads();
    kmm2<216, 36, 6, 1>(B0, C0, A0, B1, C1, A1, tid);   // E -> A (BL dead)
    __syncthreads();

    // epilogue: out[s,o] = sum_e E[e]*(ca*w0[e,o]+cb*w1[e,o]); shared q loads
    {
        const float a0 = cfa[0][10], b0 = cfb[0][10];
        const float a1 = cfa[1][10], b1 = cfb[1][10];
        const float* __restrict__ w0 = pw.w[10];
        const float* __restrict__ w1 = w0 + 12960;
        float p0[10], p1[10];
#pragma unroll
        for (int o = 0; o < 10; o++) { p0[o] = 0.f; p1[o] = 0.f; }
        for (int e = tid; e < 1296; e += NS) {
            const float E0 = A0[e];
            const float E1 = A1[e];
            const float* __restrict__ q0 = w0 + e * 10;
            const float* __restrict__ q1 = w1 + e * 10;
#pragma unroll
            for (int o = 0; o < 10; o++) {
                const float v0 = q0[o], v1 = q1[o];
                p0[o] += E0 * (a0 * v0 + b0 * v1);
                p1[o] += E1 * (a1 * v0 + b1 * v1);
            }
        }
#pragma unroll
        for (int o = 0; o < 10; o++)
            for (int off = 32; off > 0; off >>= 1) {
                p0[o] += __shfl_down(p0[o], off, 64);
                p1[o] += __shfl_down(p1[o], off, 64);
            }
        if (tid == 0) {
            float ss0 = 0.f, ss1 = 0.f;
#pragma unroll
            for (int o = 0; o < 10; o++) { ss0 += p0[o] * p0[o]; ss1 += p1[o] * p1[o]; }
            const float i0 = 1.f / sqrtf(ss0);
            const float i1 = 1.f / sqrtf(ss1);
#pragma unroll
            for (int o = 0; o < 10; o++) {
                out[s0 * 10 + o] = p0[o] * i0;
                out[(s0 + 1) * 10 + o] = p1[o] * i1;
            }
        }
    }
}

extern "C" void kernel_launch(void* const* d_in, const int* in_sizes, int n_in,
                              void* d_out, int out_size, void* d_ws, size_t ws_size,
                              hipStream_t stream) {
    PW pw;
    for (int k = 0; k < 16; k++) {
        pw.w[k] = (const float*)d_in[1 + k];
        pw.perp[k] = in_sizes[1 + k] / 2;
    }
    float* ws = (float*)d_ws;               // 72640 floats used (~291 KB)
    prep<<<72, NT, 0, stream>>>(pw, ws);

    const float* x = (const float*)d_in[0];
    const int B = out_size / 10;            // 2048 samples
    peps_main<<<B / 2, NS, 0, stream>>>(x, pw, ws, (float*)d_out);
}